// Round 10
// baseline (2861.284 us; speedup 1.0000x reference)
//
#include <hip/hip_runtime.h>

// 2-layer LSTM encoder, v10: quad-split K + DPP allreduce (no bpermute).
//
// ROUND-9 FINDING: step time (~1500 cyc) invariant to barriers/DS-count/
// residency/drains. Remaining per-step serial chain unique to all versions:
// ds_read(h) -> FMA chain -> act -> ds_bpermute GATE-GATHER (LDS-class) ->
// c -> write -> barrier. v10 removes the LDS-class gather:
//   L1 (waves 0..3): 4 lanes per unit (quad). Lane q of unit j computes
//     partials of ALL 4 gates over K-quarter h1[16q,16q+16) (64 FMA) and
//     (q==0) x/bias terms. Quad allreduce via __shfl_xor 1,2 = DPP quad_perm
//     (VALU-class). All quad lanes redundantly activate + update c1.
//   L2 (waves 4..7): 8 lanes per unit. Lane o: h1[8o,8o+8) + h2[4o,4o+4)
//     (48 FMA). Butterfly xor1,xor2 (DPP) + xor4. Redundant c2 update.
//   One lgkm-only barrier per step (v9); batched out staging (v9);
//   x via 2-chunk LDS ring (v5); weights in named float4 regs,
//   amdgpu_waves_per_eu(2,2) (v5).
// Pipeline: iter n = l1 step n + l2 step n-1; both read h1(n-1).

#define BATCH 64
#define T 4096
#define IN_DIM 4
#define H1 64
#define H2 32
#define NTHREADS 512
#define L2E 1.442695040888963f

__device__ __forceinline__ float fast_rcp(float v){ return __builtin_amdgcn_rcpf(v); }
__device__ __forceinline__ float sigm(float s){ return fast_rcp(1.0f + exp2f(-L2E * s)); }
__device__ __forceinline__ float tanh_(float s){ return 1.0f - 2.0f * fast_rcp(exp2f(2.0f * L2E * s) + 1.0f); }

// Barrier with LDS-only drain (no vmcnt wait).
__device__ __forceinline__ void barrier_lgkm() {
    asm volatile("s_waitcnt lgkmcnt(0)" ::: "memory");
    __builtin_amdgcn_s_barrier();
}

__global__ __launch_bounds__(NTHREADS)
__attribute__((amdgpu_waves_per_eu(2, 2)))
void lstm2_v10(const float* __restrict__ x,
               const float* __restrict__ W_ih1, const float* __restrict__ W_hh1,
               const float* __restrict__ b_ih1, const float* __restrict__ b_hh1,
               const float* __restrict__ W_ih2, const float* __restrict__ W_hh2,
               const float* __restrict__ b_ih2, const float* __restrict__ b_hh2,
               float* __restrict__ out)
{
    const int b    = blockIdx.x;
    const int tid  = threadIdx.x;
    const int wave = tid >> 6;
    const int lane = tid & 63;
    const bool is_l1 = (wave < 4);

    __shared__ __align__(16) float h1buf[2][H1];
    __shared__ __align__(16) float h2buf[2][H2];
    __shared__ __align__(16) float xbuf[2][64][IN_DIM];
    __shared__ __align__(16) float obuf[2][32][H2];

    if (tid < 2 * H1)               ((float*)h1buf)[tid] = 0.0f;
    else if (tid < 2 * H1 + 2 * H2) ((float*)h2buf)[tid - 2 * H1] = 0.0f;

    // weights (named -> register-resident under waves_per_eu(2,2))
    float4 W0,W1,W2,W3,W4,W5,W6,W7,W8,W9,W10,W11,W12,W13,W14,W15;
    float4 X0,X1,X2,X3;
    float  B0,B1,B2,B3;
    int    j;
    float  c = 0.0f;
    const float4 Z4 = make_float4(0.f,0.f,0.f,0.f);
    W12 = W13 = W14 = W15 = Z4; X0 = X1 = X2 = X3 = Z4;

    if (is_l1) {
        const int q = lane & 3, u = lane >> 2;
        j = 16 * wave + u;
        // gate t row = 64*t + j ; K-slice [16q, 16q+16)
        { const float4* p = (const float4*)(W_hh1 + (size_t)(       j) * H1 + 16*q);
          W0 = p[0]; W1 = p[1]; W2 = p[2]; W3 = p[3]; }
        { const float4* p = (const float4*)(W_hh1 + (size_t)(  H1 + j) * H1 + 16*q);
          W4 = p[0]; W5 = p[1]; W6 = p[2]; W7 = p[3]; }
        { const float4* p = (const float4*)(W_hh1 + (size_t)(2*H1 + j) * H1 + 16*q);
          W8 = p[0]; W9 = p[1]; W10 = p[2]; W11 = p[3]; }
        { const float4* p = (const float4*)(W_hh1 + (size_t)(3*H1 + j) * H1 + 16*q);
          W12 = p[0]; W13 = p[1]; W14 = p[2]; W15 = p[3]; }
        if (q == 0) {   // only q0 carries x-term and bias (quad-summed later)
            X0 = *(const float4*)(W_ih1 + (size_t)(       j) * IN_DIM);
            X1 = *(const float4*)(W_ih1 + (size_t)(  H1 + j) * IN_DIM);
            X2 = *(const float4*)(W_ih1 + (size_t)(2*H1 + j) * IN_DIM);
            X3 = *(const float4*)(W_ih1 + (size_t)(3*H1 + j) * IN_DIM);
            B0 = b_ih1[j]        + b_hh1[j];
            B1 = b_ih1[H1 + j]   + b_hh1[H1 + j];
            B2 = b_ih1[2*H1 + j] + b_hh1[2*H1 + j];
            B3 = b_ih1[3*H1 + j] + b_hh1[3*H1 + j];
        } else { B0 = B1 = B2 = B3 = 0.0f; }
    } else {
        const int o = lane & 7, u = lane >> 3;
        j = 8 * (wave - 4) + u;
        // gate t row = 32*t + j ; h1-slice [8o,8o+8), h2-slice [4o,4o+4)
        { const float4* p = (const float4*)(W_ih2 + (size_t)(       j) * H1 + 8*o);
          W0 = p[0]; W1 = p[1]; }
        { const float4* p = (const float4*)(W_ih2 + (size_t)(  H2 + j) * H1 + 8*o);
          W2 = p[0]; W3 = p[1]; }
        { const float4* p = (const float4*)(W_ih2 + (size_t)(2*H2 + j) * H1 + 8*o);
          W4 = p[0]; W5 = p[1]; }
        { const float4* p = (const float4*)(W_ih2 + (size_t)(3*H2 + j) * H1 + 8*o);
          W6 = p[0]; W7 = p[1]; }
        W8  = *(const float4*)(W_hh2 + (size_t)(       j) * H2 + 4*o);
        W9  = *(const float4*)(W_hh2 + (size_t)(  H2 + j) * H2 + 4*o);
        W10 = *(const float4*)(W_hh2 + (size_t)(2*H2 + j) * H2 + 4*o);
        W11 = *(const float4*)(W_hh2 + (size_t)(3*H2 + j) * H2 + 4*o);
        if (o == 0) {
            B0 = b_ih2[j]        + b_hh2[j];
            B1 = b_ih2[H2 + j]   + b_hh2[H2 + j];
            B2 = b_ih2[2*H2 + j] + b_hh2[2*H2 + j];
            B3 = b_ih2[3*H2 + j] + b_hh2[3*H2 + j];
        } else { B0 = B1 = B2 = B3 = 0.0f; }
    }

    const float4* xptr = (const float4*)(x + (size_t)b * T * IN_DIM);
    float4 xg = Z4;
    if (wave == 0) {
        *(float4*)&xbuf[0][lane][0] = xptr[lane];   // chunk 0
        xg = xptr[64 + lane];                       // chunk 1 in flight
    }
    float* const outb = out + (size_t)b * T * H2;

    __syncthreads();

#define F4(A, W, H) do { A = fmaf((H).x,(W).x,A); A = fmaf((H).y,(W).y,A); \
                         A = fmaf((H).z,(W).z,A); A = fmaf((H).w,(W).w,A); } while (0)

    for (int n = 0; n <= T; ++n) {
        // flush sealed 32-step out tile (coalesced, off critical path)
        if (n >= 33 && (n & 31) == 1) {
            const int m0 = n - 33;
            const float* src = &obuf[(m0 >> 5) & 1][0][0];
            float2 vv = *(const float2*)(src + 2 * tid);
            *(float2*)(outb + (size_t)m0 * H2 + 2 * tid) = vv;
        }

        if (is_l1) {
            if (n < T) {
                const int s = n & 63, cch = n >> 6;
                if (s == 0 && wave == 0) {
                    *(float4*)&xbuf[(cch + 1) & 1][lane][0] = xg;
                    const int nb = (cch + 2) << 6;
                    if (nb < T) xg = xptr[nb + lane];
                }
                const float4* hv = (const float4*)h1buf[(n + 1) & 1] + 4 * (lane & 3);
                float4 h0 = hv[0], h1 = hv[1], h2 = hv[2], h3 = hv[3];
                float4 xt = *(const float4*)&xbuf[cch & 1][s][0];   // broadcast
                float a0 = B0, a1 = B1, a2 = B2, a3 = B3;
                F4(a0, X0, xt); F4(a1, X1, xt); F4(a2, X2, xt); F4(a3, X3, xt); // X=0 for q!=0
                F4(a0, W0,  h0); F4(a0, W1,  h1); F4(a0, W2,  h2); F4(a0, W3,  h3);
                F4(a1, W4,  h0); F4(a1, W5,  h1); F4(a1, W6,  h2); F4(a1, W7,  h3);
                F4(a2, W8,  h0); F4(a2, W9,  h1); F4(a2, W10, h2); F4(a2, W11, h3);
                F4(a3, W12, h0); F4(a3, W13, h1); F4(a3, W14, h2); F4(a3, W15, h3);
                // quad allreduce (DPP quad_perm -- VALU class)
                a0 += __shfl_xor(a0, 1, 64); a0 += __shfl_xor(a0, 2, 64);
                a1 += __shfl_xor(a1, 1, 64); a1 += __shfl_xor(a1, 2, 64);
                a2 += __shfl_xor(a2, 1, 64); a2 += __shfl_xor(a2, 2, 64);
                a3 += __shfl_xor(a3, 1, 64); a3 += __shfl_xor(a3, 2, 64);
                float gi = sigm(a0), gf = sigm(a1), gg = tanh_(a2), go = sigm(a3);
                c = fmaf(gf, c, gi * gg);                 // replicated across quad
                float h = go * tanh_(c);
                if ((lane & 3) == 0) h1buf[n & 1][j] = h;
            }
        } else {
            if (n >= 1) {
                const float4* hv = (const float4*)h1buf[(n + 1) & 1] + 2 * (lane & 7);
                float4 p0 = hv[0], p1 = hv[1];
                float4 p2 = ((const float4*)h2buf[n & 1])[lane & 7];  // h2(n-2)
                float a0 = B0, a1 = B1, a2 = B2, a3 = B3;
                F4(a0, W0, p0); F4(a0, W1, p1); F4(a0, W8,  p2);
                F4(a1, W2, p0); F4(a1, W3, p1); F4(a1, W9,  p2);
                F4(a2, W4, p0); F4(a2, W5, p1); F4(a2, W10, p2);
                F4(a3, W6, p0); F4(a3, W7, p1); F4(a3, W11, p2);
                // 8-lane butterfly: xor1, xor2 (DPP), xor4
                a0 += __shfl_xor(a0, 1, 64); a1 += __shfl_xor(a1, 1, 64);
                a2 += __shfl_xor(a2, 1, 64); a3 += __shfl_xor(a3, 1, 64);
                a0 += __shfl_xor(a0, 2, 64); a1 += __shfl_xor(a1, 2, 64);
                a2 += __shfl_xor(a2, 2, 64); a3 += __shfl_xor(a3, 2, 64);
                a0 += __shfl_xor(a0, 4, 64); a1 += __shfl_xor(a1, 4, 64);
                a2 += __shfl_xor(a2, 4, 64); a3 += __shfl_xor(a3, 4, 64);
                float gi = sigm(a0), gf = sigm(a1), gg = tanh_(a2), go = sigm(a3);
                c = fmaf(gf, c, gi * gg);                 // replicated across oct
                float h = go * tanh_(c);
                if ((lane & 7) == 0) {
                    const int m = n - 1;
                    h2buf[(n + 1) & 1][j] = h;
                    obuf[(m >> 5) & 1][m & 31][j] = h;
                }
            }
        }
        barrier_lgkm();
    }

    // tail flush: last tile m = T-32 .. T-1
    {
        const int m0 = T - 32;
        const float* src = &obuf[(m0 >> 5) & 1][0][0];
        float2 vv = *(const float2*)(src + 2 * tid);
        *(float2*)(outb + (size_t)m0 * H2 + 2 * tid) = vv;
    }
#undef F4
}

extern "C" void kernel_launch(void* const* d_in, const int* in_sizes, int n_in,
                              void* d_out, int out_size, void* d_ws, size_t ws_size,
                              hipStream_t stream) {
    const float* x     = (const float*)d_in[0];
    const float* W_ih1 = (const float*)d_in[1];
    const float* W_hh1 = (const float*)d_in[2];
    const float* b_ih1 = (const float*)d_in[3];
    const float* b_hh1 = (const float*)d_in[4];
    const float* W_ih2 = (const float*)d_in[5];
    const float* W_hh2 = (const float*)d_in[6];
    const float* b_ih2 = (const float*)d_in[7];
    const float* b_hh2 = (const float*)d_in[8];
    float* out = (float*)d_out;

    lstm2_v10<<<dim3(BATCH), dim3(NTHREADS), 0, stream>>>(
        x, W_ih1, W_hh1, b_ih1, b_hh1, W_ih2, W_hh2, b_ih2, b_hh2, out);
}